// Round 1
// baseline (1526.408 us; speedup 1.0000x reference)
//
#include <hip/hip_runtime.h>
#include <hip/hip_bf16.h>
#include <cstdint>

// QuantizedLinear: Y[M,N] = X[M,K] . W^T[K,N] + bias, W dequant = (q - zp)*scale
// M = 4*2048 = 8192, N = 16384, K = 4096.
// Strategy: prepass converts X (f32->bf16) and W ((q-zp)*scale -> bf16) into d_ws,
// then m97-structure bf16 MFMA GEMM (128x128 tile, BK=32, global_load_lds width16).

#define M_DIM 8192
#define N_DIM 16384
#define K_DIM 4096

using short8 = __attribute__((ext_vector_type(8))) short;
using bf16x8 = short8;                                   // 8 bf16 in 4 VGPRs
using f32x4  = __attribute__((ext_vector_type(4))) float;

__device__ __forceinline__ unsigned short f2bf(float f) {
    union { float f; unsigned int u; } v; v.f = f;
    unsigned int lsb = (v.u >> 16) & 1u;
    v.u += 0x7fffu + lsb;          // round-to-nearest-even (inputs finite)
    return (unsigned short)(v.u >> 16);
}

__global__ void cvt_x_kernel(const float* __restrict__ x, unsigned short* __restrict__ o,
                             long long n) {
    long long i = (long long)blockIdx.x * blockDim.x + threadIdx.x;
    long long stride = (long long)gridDim.x * blockDim.x * 4;
    for (long long idx = i * 4; idx < n; idx += stride) {
        float4 v = *(const float4*)(x + idx);
        ushort4 r;
        r.x = f2bf(v.x); r.y = f2bf(v.y); r.z = f2bf(v.z); r.w = f2bf(v.w);
        *(ushort4*)(o + idx) = r;
    }
}

__global__ void cvt_w_kernel(const int* __restrict__ q, unsigned short* __restrict__ o,
                             const float* __restrict__ sp, const float* __restrict__ zp,
                             long long n) {
    float s = sp[0], z = zp[0];
    long long i = (long long)blockIdx.x * blockDim.x + threadIdx.x;
    long long stride = (long long)gridDim.x * blockDim.x * 4;
    for (long long idx = i * 4; idx < n; idx += stride) {
        int4 v = *(const int4*)(q + idx);
        ushort4 r;
        r.x = f2bf(((float)v.x - z) * s);
        r.y = f2bf(((float)v.y - z) * s);
        r.z = f2bf(((float)v.z - z) * s);
        r.w = f2bf(((float)v.w - z) * s);
        *(ushort4*)(o + idx) = r;
    }
}

// m97-structure GEMM: A[M][K] bf16, B[N][K] bf16 (i.e. B^T input), C[M][N] f32 (+bias)
// 128x128 tile, BK=32, 256 threads = 4 waves in 2x2, each wave 64x64 (4x4 16x16 frags).
__global__ __launch_bounds__(256) void gemm_kernel(const unsigned short* __restrict__ A,
                                                   const unsigned short* __restrict__ B,
                                                   const float* __restrict__ bias,
                                                   float* __restrict__ C) {
    __shared__ __align__(16) unsigned short sA[128 * 32];
    __shared__ __align__(16) unsigned short sB[128 * 32];

    const int tid  = threadIdx.x;
    const int wave = tid >> 6;
    const int lane = tid & 63;

    // XCD-aware swizzle: nwg = 64*128 = 8192, divisible by 8 -> bijective
    const int nwg = (M_DIM / 128) * (N_DIM / 128);
    const int cpx = nwg >> 3;
    const int bid = blockIdx.x;
    const int swz = (bid & 7) * cpx + (bid >> 3);
    const int tm = swz / (N_DIM / 128);
    const int tn = swz % (N_DIM / 128);

    const int rowBase = tm * 128;
    const int colBase = tn * 128;
    const int wr = wave >> 1, wc = wave & 1;

    f32x4 acc[4][4] = {};

    const unsigned short* Abase = A + (size_t)rowBase * K_DIM;
    const unsigned short* Bbase = B + (size_t)colBase * K_DIM;

    // staging geometry: per chunk (64 rows), wave covers 16 rows; lane l -> row l/4, col (l&3)*8
    const int st_row = lane >> 2;
    const int st_col = (lane & 3) * 8;

    const int fr = lane & 15;        // fragment row (A) / col-row (B)
    const int ko = (lane >> 4) * 8;  // fragment k offset

    for (int k0 = 0; k0 < K_DIM; k0 += 32) {
        #pragma unroll
        for (int c = 0; c < 2; ++c) {
            const int rr = c * 64 + wave * 16;   // wave-uniform row base
            const unsigned short* ga = Abase + (size_t)(rr + st_row) * K_DIM + k0 + st_col;
            const unsigned short* gb = Bbase + (size_t)(rr + st_row) * K_DIM + k0 + st_col;
            __builtin_amdgcn_global_load_lds(
                (const __attribute__((address_space(1))) void*)ga,
                (__attribute__((address_space(3))) void*)(sA + rr * 32), 16, 0, 0);
            __builtin_amdgcn_global_load_lds(
                (const __attribute__((address_space(1))) void*)gb,
                (__attribute__((address_space(3))) void*)(sB + rr * 32), 16, 0, 0);
        }
        __syncthreads();   // compiler drains vmcnt before s_barrier

        bf16x8 af[4], bfr[4];
        #pragma unroll
        for (int m = 0; m < 4; ++m)
            af[m] = *(const bf16x8*)(sA + (wr * 64 + m * 16 + fr) * 32 + ko);
        #pragma unroll
        for (int n = 0; n < 4; ++n)
            bfr[n] = *(const bf16x8*)(sB + (wc * 64 + n * 16 + fr) * 32 + ko);

        #pragma unroll
        for (int m = 0; m < 4; ++m)
            #pragma unroll
            for (int n = 0; n < 4; ++n)
                acc[m][n] = __builtin_amdgcn_mfma_f32_16x16x32_bf16(af[m], bfr[n], acc[m][n], 0, 0, 0);

        __syncthreads();
    }

    // epilogue: C/D layout col = lane&15, row = (lane>>4)*4 + j
    const int cr = (lane >> 4) * 4;
    const int cc = lane & 15;
    #pragma unroll
    for (int n = 0; n < 4; ++n) {
        const int col = colBase + wc * 64 + n * 16 + cc;
        const float b = bias[col];
        #pragma unroll
        for (int m = 0; m < 4; ++m) {
            const int row0 = rowBase + wr * 64 + m * 16 + cr;
            #pragma unroll
            for (int j = 0; j < 4; ++j)
                C[(size_t)(row0 + j) * N_DIM + col] = acc[m][n][j] + b;
        }
    }
}

// Fallback (only if ws_size too small): basic LDS-tiled f32 GEMM, correct but slow.
__global__ void gemm_naive(const float* __restrict__ x, const int* __restrict__ wq,
                           const float* __restrict__ sp, const float* __restrict__ zp,
                           const float* __restrict__ bias, float* __restrict__ out) {
    __shared__ float sX[32][33];
    __shared__ float sW[32][33];
    const float s = sp[0], z = zp[0];
    const int tx = threadIdx.x & 15, ty = threadIdx.x >> 4;
    const int row0 = blockIdx.y * 32, col0 = blockIdx.x * 32;
    float acc[2][2] = {};
    for (int k0 = 0; k0 < K_DIM; k0 += 32) {
        for (int i = threadIdx.x; i < 32 * 32; i += 256) {
            int r = i >> 5, c = i & 31;
            sX[r][c] = x[(size_t)(row0 + r) * K_DIM + k0 + c];
            sW[r][c] = ((float)wq[(size_t)(col0 + r) * K_DIM + k0 + c] - z) * s;
        }
        __syncthreads();
        #pragma unroll
        for (int k = 0; k < 32; ++k) {
            float xa0 = sX[ty * 2][k], xa1 = sX[ty * 2 + 1][k];
            float wb0 = sW[tx * 2][k], wb1 = sW[tx * 2 + 1][k];
            acc[0][0] += xa0 * wb0; acc[0][1] += xa0 * wb1;
            acc[1][0] += xa1 * wb0; acc[1][1] += xa1 * wb1;
        }
        __syncthreads();
    }
    #pragma unroll
    for (int i = 0; i < 2; ++i)
        #pragma unroll
        for (int j = 0; j < 2; ++j)
            out[(size_t)(row0 + ty * 2 + i) * N_DIM + (col0 + tx * 2 + j)] =
                acc[i][j] + bias[col0 + tx * 2 + j];
}

extern "C" void kernel_launch(void* const* d_in, const int* in_sizes, int n_in,
                              void* d_out, int out_size, void* d_ws, size_t ws_size,
                              hipStream_t stream) {
    const float* x     = (const float*)d_in[0];
    const int*   wq    = (const int*)d_in[1];
    const float* scale = (const float*)d_in[2];
    const float* zp    = (const float*)d_in[3];
    const float* bias  = (const float*)d_in[4];
    float* out = (float*)d_out;

    const size_t needA = (size_t)M_DIM * K_DIM * sizeof(unsigned short);  //  64 MiB
    const size_t needB = (size_t)N_DIM * K_DIM * sizeof(unsigned short);  // 128 MiB

    if (ws_size >= needA + needB) {
        unsigned short* xb = (unsigned short*)d_ws;
        unsigned short* wb = xb + (size_t)M_DIM * K_DIM;
        cvt_x_kernel<<<2048, 256, 0, stream>>>(x, xb, (long long)M_DIM * K_DIM);
        cvt_w_kernel<<<2048, 256, 0, stream>>>(wq, wb, scale, zp, (long long)N_DIM * K_DIM);
        gemm_kernel<<<(M_DIM / 128) * (N_DIM / 128), 256, 0, stream>>>(xb, wb, bias, out);
    } else {
        dim3 grid(N_DIM / 32, M_DIM / 32);
        gemm_naive<<<grid, 256, 0, stream>>>(x, wq, scale, zp, bias, out);
    }
}

// Round 2
// 1057.332 us; speedup vs baseline: 1.4436x; 1.4436x over previous
//
#include <hip/hip_runtime.h>
#include <hip/hip_bf16.h>
#include <cstdint>

// QuantizedLinear: Y[M,N] = X[M,K] . W^T + bias.  M=8192, N=16384, K=4096.
// Prepass: X f32->bf16, W (q-zp)*scale->bf16 into d_ws.
// GEMM: 256x256 tile, BK=64, 8 waves (2Mx4N), 128KiB LDS dbuf, 8-phase schedule
// (T2 xor-swizzle + T3/T4 counted vmcnt + T5 setprio), XCD-swizzled grid.

#define M_DIM 8192
#define N_DIM 16384
#define K_DIM 4096
#define NT (K_DIM / 64)   // 64 k-tiles

using bf16x8 = __attribute__((ext_vector_type(8))) short;
using f32x4  = __attribute__((ext_vector_type(4))) float;

__device__ __forceinline__ unsigned short f2bf(float f) {
    union { float f; unsigned int u; } v; v.f = f;
    unsigned int lsb = (v.u >> 16) & 1u;
    v.u += 0x7fffu + lsb;
    return (unsigned short)(v.u >> 16);
}

__global__ void cvt_x_kernel(const float* __restrict__ x, unsigned short* __restrict__ o,
                             long long n) {
    long long i = (long long)blockIdx.x * blockDim.x + threadIdx.x;
    long long stride = (long long)gridDim.x * blockDim.x * 4;
    for (long long idx = i * 4; idx < n; idx += stride) {
        float4 v = *(const float4*)(x + idx);
        ushort4 r;
        r.x = f2bf(v.x); r.y = f2bf(v.y); r.z = f2bf(v.z); r.w = f2bf(v.w);
        *(ushort4*)(o + idx) = r;
    }
}

__global__ void cvt_w_kernel(const int* __restrict__ q, unsigned short* __restrict__ o,
                             const float* __restrict__ sp, const float* __restrict__ zp,
                             long long n) {
    float s = sp[0], z = zp[0];
    long long i = (long long)blockIdx.x * blockDim.x + threadIdx.x;
    long long stride = (long long)gridDim.x * blockDim.x * 4;
    for (long long idx = i * 4; idx < n; idx += stride) {
        int4 v = *(const int4*)(q + idx);
        ushort4 r;
        r.x = f2bf(((float)v.x - z) * s);
        r.y = f2bf(((float)v.y - z) * s);
        r.z = f2bf(((float)v.z - z) * s);
        r.w = f2bf(((float)v.w - z) * s);
        *(ushort4*)(o + idx) = r;
    }
}

#define SB() __builtin_amdgcn_sched_barrier(0)

__device__ __forceinline__ void barrier_() {
    SB();
    asm volatile("" ::: "memory");
    __builtin_amdgcn_s_barrier();
    asm volatile("" ::: "memory");
    SB();
}

// Stage one 128-row x 64-col half-tile (16 KiB) via 2x global_load_lds width-16.
// l0 must be wave-uniform (unit base + wave*512 elems); lanes write lane*16B.
// Global source is inverse-swizzled so that swizzled reads see linear data.
__device__ __forceinline__ void stage_half(const unsigned short* g0, unsigned short* l0) {
    __builtin_amdgcn_global_load_lds((const __attribute__((address_space(1))) void*)g0,
                                     (__attribute__((address_space(3))) void*)l0, 16, 0, 0);
    __builtin_amdgcn_global_load_lds(
        (const __attribute__((address_space(1))) void*)(g0 + (size_t)64 * K_DIM),
        (__attribute__((address_space(3))) void*)(l0 + 4096), 16, 0, 0);
}

__global__ __launch_bounds__(512, 2) void gemm256_kernel(const unsigned short* __restrict__ A,
                                                         const unsigned short* __restrict__ B,
                                                         const float* __restrict__ bias,
                                                         float* __restrict__ C) {
    extern __shared__ unsigned short smem[];   // 128 KiB: 2 bufs x (A 16K elems + B 16K elems)

    const int tid  = threadIdx.x;
    const int wave = tid >> 6;
    const int lane = tid & 63;
    const int fr = lane & 15, hi = lane >> 4;
    const int wr = wave >> 2, wc = wave & 3;

    // XCD-aware bijective swizzle: nwg = 32*64 = 2048, divisible by 8.
    const int nwg = (M_DIM / 256) * (N_DIM / 256);
    const int cpx = nwg >> 3;
    const int swz = (blockIdx.x & 7) * cpx + (blockIdx.x >> 3);
    const int ntn = N_DIM / 256;
    const int tileRow = (swz / ntn) * 256;
    const int tileCol = (swz % ntn) * 256;

    // ---- staging addressing (per thread) ----
    // LDS linear within unit: byte = j*8192 + tid*16 -> row = j*64 + tid>>3, colbyte=(tid&7)*16
    // content at swizzled source col: ((tid&7) ^ ((tid>>3)&7)) * 8 elems
    const size_t goff = (size_t)(tid >> 3) * K_DIM + (((tid & 7) ^ ((tid >> 3) & 7)) * 8);
    const unsigned short* Au = A + (size_t)tileRow * K_DIM + goff;
    const unsigned short* Bu = B + (size_t)tileCol * K_DIM + goff;
    unsigned short* lw = smem + wave * 512;   // wave-uniform lane base

    // ---- read addressing ----
    // swizzled read col (elems): (s*32 + hi*8) ^ ((fr&7)<<3)
    const int c0 = (0 * 32 + hi * 8) ^ ((fr & 7) << 3);
    const int c1 = (1 * 32 + hi * 8) ^ ((fr & 7) << 3);
    const int aoff = wr * 8192 + fr * 64;                                  // + m*1024 + c{s}
    const int boff = 16384 + (wc >> 1) * 8192 + ((wc & 1) * 64 + fr) * 64; // + n*1024 + c{s}

    f32x4 acc[8][4] = {};
    bf16x8 ar[4][2], b0r[2][2], b1r[2][2];

    // ---- prologue: tile0 full (buf0), tile1 Bh0+Ah0 (buf1) ----
    stage_half(Au, lw);
    stage_half(Au + (size_t)128 * K_DIM, lw + 8192);
    stage_half(Bu, lw + 16384);
    stage_half(Bu + (size_t)128 * K_DIM, lw + 16384 + 8192);
    stage_half(Bu + 64, lw + 32768 + 16384);
    stage_half(Au + 64, lw + 32768);
    SB();
    asm volatile("s_waitcnt vmcnt(4)" ::: "memory");   // tile0 arrived
    barrier_();

    for (int t = 0; t < NT; ++t) {
        unsigned short* sb = smem + (t & 1) * 32768;
        unsigned short* snext = smem + ((t + 1) & 1) * 32768;
        const int kn1 = (t + 1) * 64, kn2 = (t + 2) * 64;

        // ================= P1: read A-half(m0-3) + B(n0-1); stage t+1.Ah1 =================
        #pragma unroll
        for (int m = 0; m < 4; ++m) {
            ar[m][0] = *(const bf16x8*)(sb + aoff + m * 1024 + c0);
            ar[m][1] = *(const bf16x8*)(sb + aoff + m * 1024 + c1);
        }
        #pragma unroll
        for (int n = 0; n < 2; ++n) {
            b0r[n][0] = *(const bf16x8*)(sb + boff + n * 1024 + c0);
            b0r[n][1] = *(const bf16x8*)(sb + boff + n * 1024 + c1);
        }
        if (t + 1 < NT) stage_half(Au + (size_t)128 * K_DIM + kn1, snext + 8192 + wave * 512);
        barrier_();
        asm volatile("s_waitcnt lgkmcnt(0)" ::: "memory");
        SB();
        __builtin_amdgcn_s_setprio(1);
        #pragma unroll
        for (int m = 0; m < 4; ++m)
            #pragma unroll
            for (int n = 0; n < 2; ++n) {
                acc[m][n] = __builtin_amdgcn_mfma_f32_16x16x32_bf16(ar[m][0], b0r[n][0], acc[m][n], 0, 0, 0);
                acc[m][n] = __builtin_amdgcn_mfma_f32_16x16x32_bf16(ar[m][1], b0r[n][1], acc[m][n], 0, 0, 0);
            }
        __builtin_amdgcn_s_setprio(0);
        barrier_();

        // ================= P2: read B(n2-3); stage t+1.Bh1 =================
        #pragma unroll
        for (int n = 0; n < 2; ++n) {
            b1r[n][0] = *(const bf16x8*)(sb + boff + (n + 2) * 1024 + c0);
            b1r[n][1] = *(const bf16x8*)(sb + boff + (n + 2) * 1024 + c1);
        }
        if (t + 1 < NT) stage_half(Bu + (size_t)128 * K_DIM + kn1, snext + 16384 + 8192 + wave * 512);
        barrier_();
        asm volatile("s_waitcnt lgkmcnt(0)" ::: "memory");
        SB();
        __builtin_amdgcn_s_setprio(1);
        #pragma unroll
        for (int m = 0; m < 4; ++m)
            #pragma unroll
            for (int n = 0; n < 2; ++n) {
                acc[m][n + 2] = __builtin_amdgcn_mfma_f32_16x16x32_bf16(ar[m][0], b1r[n][0], acc[m][n + 2], 0, 0, 0);
                acc[m][n + 2] = __builtin_amdgcn_mfma_f32_16x16x32_bf16(ar[m][1], b1r[n][1], acc[m][n + 2], 0, 0, 0);
            }
        __builtin_amdgcn_s_setprio(0);
        barrier_();

        // ================= P3: read A-half(m4-7); stage t+2.Bh0 =================
        #pragma unroll
        for (int m = 0; m < 4; ++m) {
            ar[m][0] = *(const bf16x8*)(sb + aoff + 4096 + m * 1024 + c0);
            ar[m][1] = *(const bf16x8*)(sb + aoff + 4096 + m * 1024 + c1);
        }
        if (t + 2 < NT) stage_half(Bu + kn2, sb + 16384 + wave * 512);
        barrier_();
        asm volatile("s_waitcnt lgkmcnt(0)" ::: "memory");
        SB();
        __builtin_amdgcn_s_setprio(1);
        #pragma unroll
        for (int m = 0; m < 4; ++m)
            #pragma unroll
            for (int n = 0; n < 2; ++n) {
                acc[m + 4][n + 2] = __builtin_amdgcn_mfma_f32_16x16x32_bf16(ar[m][0], b1r[n][0], acc[m + 4][n + 2], 0, 0, 0);
                acc[m + 4][n + 2] = __builtin_amdgcn_mfma_f32_16x16x32_bf16(ar[m][1], b1r[n][1], acc[m + 4][n + 2], 0, 0, 0);
            }
        __builtin_amdgcn_s_setprio(0);
        barrier_();

        // ================= P4: stage t+2.Ah0; MFMA; counted vmcnt =================
        if (t + 2 < NT) stage_half(Au + kn2, sb + wave * 512);
        barrier_();
        __builtin_amdgcn_s_setprio(1);
        #pragma unroll
        for (int m = 0; m < 4; ++m)
            #pragma unroll
            for (int n = 0; n < 2; ++n) {
                acc[m + 4][n] = __builtin_amdgcn_mfma_f32_16x16x32_bf16(ar[m][0], b0r[n][0], acc[m + 4][n], 0, 0, 0);
                acc[m + 4][n] = __builtin_amdgcn_mfma_f32_16x16x32_bf16(ar[m][1], b0r[n][1], acc[m + 4][n], 0, 0, 0);
            }
        __builtin_amdgcn_s_setprio(0);
        SB();
        if (t + 2 < NT) {
            asm volatile("s_waitcnt vmcnt(4)" ::: "memory");   // t+1 fully arrived
        } else if (t + 1 < NT) {
            asm volatile("s_waitcnt vmcnt(0)" ::: "memory");   // drain tail
        }
        barrier_();
    }

    // ---- epilogue: C/D layout col = lane&15, row = (lane>>4)*4 + j ----
    #pragma unroll
    for (int m = 0; m < 8; ++m) {
        const int grow0 = tileRow + wr * 128 + m * 16 + hi * 4;
        #pragma unroll
        for (int n = 0; n < 4; ++n) {
            const int gcol = tileCol + wc * 64 + n * 16 + fr;
            const float bv = bias[gcol];
            #pragma unroll
            for (int j = 0; j < 4; ++j)
                C[(size_t)(grow0 + j) * N_DIM + gcol] = acc[m][n][j] + bv;
        }
    }
}

// Fallback (only if ws too small): basic LDS-tiled f32 GEMM.
__global__ void gemm_naive(const float* __restrict__ x, const int* __restrict__ wq,
                           const float* __restrict__ sp, const float* __restrict__ zp,
                           const float* __restrict__ bias, float* __restrict__ out) {
    __shared__ float sX[32][33];
    __shared__ float sW[32][33];
    const float s = sp[0], z = zp[0];
    const int tx = threadIdx.x & 15, ty = threadIdx.x >> 4;
    const int row0 = blockIdx.y * 32, col0 = blockIdx.x * 32;
    float acc[2][2] = {};
    for (int k0 = 0; k0 < K_DIM; k0 += 32) {
        for (int i = threadIdx.x; i < 32 * 32; i += 256) {
            int r = i >> 5, c = i & 31;
            sX[r][c] = x[(size_t)(row0 + r) * K_DIM + k0 + c];
            sW[r][c] = ((float)wq[(size_t)(col0 + r) * K_DIM + k0 + c] - z) * s;
        }
        __syncthreads();
        #pragma unroll
        for (int k = 0; k < 32; ++k) {
            float xa0 = sX[ty * 2][k], xa1 = sX[ty * 2 + 1][k];
            float wb0 = sW[tx * 2][k], wb1 = sW[tx * 2 + 1][k];
            acc[0][0] += xa0 * wb0; acc[0][1] += xa0 * wb1;
            acc[1][0] += xa1 * wb0; acc[1][1] += xa1 * wb1;
        }
        __syncthreads();
    }
    #pragma unroll
    for (int i = 0; i < 2; ++i)
        #pragma unroll
        for (int j = 0; j < 2; ++j)
            out[(size_t)(row0 + ty * 2 + i) * N_DIM + (col0 + tx * 2 + j)] =
                acc[i][j] + bias[col0 + tx * 2 + j];
}

extern "C" void kernel_launch(void* const* d_in, const int* in_sizes, int n_in,
                              void* d_out, int out_size, void* d_ws, size_t ws_size,
                              hipStream_t stream) {
    const float* x     = (const float*)d_in[0];
    const int*   wq    = (const int*)d_in[1];
    const float* scale = (const float*)d_in[2];
    const float* zp    = (const float*)d_in[3];
    const float* bias  = (const float*)d_in[4];
    float* out = (float*)d_out;

    const size_t needA = (size_t)M_DIM * K_DIM * sizeof(unsigned short);
    const size_t needB = (size_t)N_DIM * K_DIM * sizeof(unsigned short);

    if (ws_size >= needA + needB) {
        unsigned short* xb = (unsigned short*)d_ws;
        unsigned short* wb = xb + (size_t)M_DIM * K_DIM;
        cvt_x_kernel<<<2048, 256, 0, stream>>>(x, xb, (long long)M_DIM * K_DIM);
        cvt_w_kernel<<<2048, 256, 0, stream>>>(wq, wb, scale, zp, (long long)N_DIM * K_DIM);
        (void)hipFuncSetAttribute((const void*)gemm256_kernel,
                                  hipFuncAttributeMaxDynamicSharedMemorySize, 131072);
        gemm256_kernel<<<(M_DIM / 256) * (N_DIM / 256), 512, 131072, stream>>>(xb, wb, bias, out);
    } else {
        dim3 grid(N_DIM / 32, M_DIM / 32);
        gemm_naive<<<grid, 256, 0, stream>>>(x, wq, scale, zp, bias, out);
    }
}